// Round 13
// baseline (284.494 us; speedup 1.0000x reference)
//
#include <hip/hip_runtime.h>
#include <math.h>

// Problem constants: B=256, H=W=64, P=16, PH=PW=16, ZD=32, HD=1024, UD=3, IN=4096
#define SPLITK1 16   // layer-1 split-K (256 blocks at 128x128 tiles)
#define SPLITK2 16   // layer-2 split-K (256 blocks, nkt=1)

typedef __bf16 bf16x8 __attribute__((ext_vector_type(8)));
typedef float  f32x4  __attribute__((ext_vector_type(4)));

__device__ inline unsigned short bf16rne(float x) {
    unsigned int u = __float_as_uint(x);
    unsigned int r = u + 0x7FFFu + ((u >> 16) & 1u);
    return (unsigned short)(r >> 16);
}
__device__ inline float bf16tof(unsigned short h) {
    return __uint_as_float(((unsigned int)h) << 16);
}

// ---------------------------------------------------------------------------
// prep_all: fused independent preprocessing.
// ---------------------------------------------------------------------------
__global__ __launch_bounds__(256) void prep_all(
    const float* __restrict__ inputs,
    const float* __restrict__ W1, const float* __restrict__ W2,
    const float* __restrict__ Wum, const float* __restrict__ Wuv,
    const float* __restrict__ Wgm, const float* __restrict__ Wgv,
    const float* __restrict__ Wz,
    unsigned short* __restrict__ Ahi, unsigned short* __restrict__ Alo,
    unsigned short* __restrict__ W1Thi, unsigned short* __restrict__ W1Tlo,
    unsigned short* __restrict__ W2Thi, unsigned short* __restrict__ W2Tlo,
    float* __restrict__ WT, float* __restrict__ partsb)
{
    __shared__ float t[32][33];
    int bid = blockIdx.x;
    int tid = threadIdx.x;
    if (bid < 4096 || (bid >= 8192 && bid < 9216)) {
        const float* W = (bid < 4096) ? W1 : W2;
        unsigned short* Thi = (bid < 4096) ? W1Thi : W2Thi;
        unsigned short* Tlo = (bid < 4096) ? W1Tlo : W2Tlo;
        int K = (bid < 4096) ? 4096 : 1024;
        int b2 = (bid < 4096) ? bid : (bid - 8192);
        int n0 = (b2 & 31) * 32, k0 = (b2 >> 5) * 32;
        int c = tid & 31, r0 = tid >> 5;
#pragma unroll
        for (int i = 0; i < 4; i++)
            t[r0 + 8 * i][c] = W[(size_t)(k0 + r0 + 8 * i) * 1024 + n0 + c];
        __syncthreads();
        int kk = tid & 31, n1 = tid >> 5;
#pragma unroll
        for (int i = 0; i < 4; i++) {
            float x = t[kk][n1 + 8 * i];
            unsigned short h = bf16rne(x);
            unsigned short l = bf16rne(x - bf16tof(h));
            size_t o = (size_t)(n0 + n1 + 8 * i) * K + k0 + kk;
            Thi[o] = h;
            Tlo[o] = l;
        }
    } else if (bid < 8192) {
        int id = (bid - 4096) * 256 + tid;
        float x = inputs[id];
        unsigned short h = bf16rne(x);
        Ahi[id] = h;
        Alo[id] = bf16rne(x - bf16tof(h));
    } else if (bid < 9624) {
        int id = (bid - 9216) * 256 + tid;
        int o = id >> 10;
        int k = id & 1023;
        float v;
        if (o < 48)       v = Wum[k * 48 + o];
        else if (o < 96)  v = Wuv[k * 48 + (o - 48)];
        else if (o < 99)  v = Wgm[k * 3 + (o - 96)];
        else              v = Wgv[k * 3 + (o - 99)];
        WT[id] = v;
    } else {
        int idx = (bid - 9624) * 256 + tid;
        float s = 0.f;
#pragma unroll
        for (int z = 0; z < 32; z++) s += Wz[z * 4096 + idx];
        partsb[idx] = 1.f / (1.f + expf(-s));
    }
}

// ---------------------------------------------------------------------------
// GEMM bf16x3, 128x128 block tile. __launch_bounds__(256, 2) gives the
// register allocator a 256-VGPR budget (acc 64 + frags 64 + prefetch 64 +
// addressing fits) -- r12's spill came from the default occupancy target
// capping at 96 VGPRs. 2 blocks/CU (64 KB LDS) x 4 waves = 8 waves/CU.
// Per ks: 16 ds_read_b128 vs 48 MFMA -> MFMA-bound.
// grid = (N/128=8, M/128=2, SPLITK).
// ---------------------------------------------------------------------------
__global__ __launch_bounds__(256, 2) void gemm_bf16x3_128(
    const unsigned short* __restrict__ Ahi, const unsigned short* __restrict__ Alo,
    const unsigned short* __restrict__ Bhi, const unsigned short* __restrict__ Blo,
    float* __restrict__ psum, int K, int kchunk)
{
    __shared__ unsigned short Ah[8192], Al[8192], Bh[8192], Bl[8192];
    int tid = threadIdx.x;
    int n0 = blockIdx.x * 128, m0 = blockIdx.y * 128;
    int kb = blockIdx.z * kchunk;
    int wid = tid >> 6, lane = tid & 63;
    int wm = wid & 1, wn = wid >> 1;
    int lm = lane & 15, q = lane >> 4;
    int sw = lm & 7;

    int ls[4];
    size_t gA[4], gB[4];
#pragma unroll
    for (int i = 0; i < 4; i++) {
        int id = tid + (i << 8);
        int row = id >> 3, ch = id & 7;
        ls[i] = row * 64 + 8 * (ch ^ (row & 7));
        gA[i] = (size_t)(m0 + row) * K + kb + ch * 8;
        gB[i] = (size_t)(n0 + row) * K + kb + ch * 8;
    }

    f32x4 acc[4][4] = {};

    int nkt = kchunk >> 6;
    uint4 pah[4], pal[4], pbh[4], pbl[4];
#pragma unroll
    for (int i = 0; i < 4; i++) {
        pah[i] = *(const uint4*)(Ahi + gA[i]);
        pal[i] = *(const uint4*)(Alo + gA[i]);
        pbh[i] = *(const uint4*)(Bhi + gB[i]);
        pbl[i] = *(const uint4*)(Blo + gB[i]);
    }

    for (int kt = 0; kt < nkt; kt++) {
        __syncthreads();
#pragma unroll
        for (int i = 0; i < 4; i++) {
            *(uint4*)(Ah + ls[i]) = pah[i];
            *(uint4*)(Al + ls[i]) = pal[i];
            *(uint4*)(Bh + ls[i]) = pbh[i];
            *(uint4*)(Bl + ls[i]) = pbl[i];
        }
        __syncthreads();
        if (kt + 1 < nkt) {
            size_t o = (size_t)(kt + 1) * 64;
#pragma unroll
            for (int i = 0; i < 4; i++) {
                pah[i] = *(const uint4*)(Ahi + gA[i] + o);
                pal[i] = *(const uint4*)(Alo + gA[i] + o);
                pbh[i] = *(const uint4*)(Bhi + gB[i] + o);
                pbl[i] = *(const uint4*)(Blo + gB[i] + o);
            }
        }
#pragma unroll
        for (int ks = 0; ks < 2; ks++) {
            int cidx = 8 * (((ks << 2) + q) ^ sw);
            bf16x8 afh[4], afl[4], bfh[4], bfl[4];
#pragma unroll
            for (int t = 0; t < 4; t++) {
                int ra = (wm * 64 + t * 16 + lm) * 64 + cidx;
                int rb = (wn * 64 + t * 16 + lm) * 64 + cidx;
                afh[t] = *(const bf16x8*)(Ah + ra);
                afl[t] = *(const bf16x8*)(Al + ra);
                bfh[t] = *(const bf16x8*)(Bh + rb);
                bfl[t] = *(const bf16x8*)(Bl + rb);
            }
#pragma unroll
            for (int mt = 0; mt < 4; mt++)
#pragma unroll
                for (int nt = 0; nt < 4; nt++) {
                    acc[mt][nt] = __builtin_amdgcn_mfma_f32_16x16x32_bf16(afh[mt], bfh[nt], acc[mt][nt], 0, 0, 0);
                    acc[mt][nt] = __builtin_amdgcn_mfma_f32_16x16x32_bf16(afh[mt], bfl[nt], acc[mt][nt], 0, 0, 0);
                    acc[mt][nt] = __builtin_amdgcn_mfma_f32_16x16x32_bf16(afl[mt], bfh[nt], acc[mt][nt], 0, 0, 0);
                }
        }
    }

    // Epilogue: C/D layout col = lane&15, row = q*4 + reg
    float* op = psum + (size_t)blockIdx.z * (256 * 1024);
#pragma unroll
    for (int mt = 0; mt < 4; mt++)
#pragma unroll
        for (int nt = 0; nt < 4; nt++) {
            int row = m0 + wm * 64 + mt * 16 + q * 4;
            int col = n0 + wn * 64 + nt * 16 + lm;
#pragma unroll
            for (int r = 0; r < 4; r++)
                op[(size_t)(row + r) * 1024 + col] = acc[mt][nt][r];
        }
}

// ---------------------------------------------------------------------------
// Reduce layer-1 partials (S slices) + bias + relu -> bf16 hi/lo split.
// ---------------------------------------------------------------------------
__global__ __launch_bounds__(256) void reduce_bias_relu_split(
    const float* __restrict__ psum, const float* __restrict__ bias,
    unsigned short* __restrict__ hi, unsigned short* __restrict__ lo, int S)
{
    int i = blockIdx.x * 256 + threadIdx.x;
    float v = 0.f;
    for (int s = 0; s < S; s++) v += psum[(size_t)s * 262144 + i];
    v += bias[i & 1023];
    v = fmaxf(v, 0.f);
    unsigned short h = bf16rne(v);
    hi[i] = h;
    lo[i] = bf16rne(v - bf16tof(h));
}

// ---------------------------------------------------------------------------
// heads_v3: fused layer-2 split-K reduce (S slices) + head matvecs.
// ---------------------------------------------------------------------------
__global__ __launch_bounds__(512) void heads_v3(
    const float* __restrict__ psum, const float* __restrict__ b2,
    const float* __restrict__ WT,
    const float* __restrict__ bum, const float* __restrict__ buv,
    const float* __restrict__ bgm, const float* __restrict__ bgv,
    const float* __restrict__ eps_u, const float* __restrict__ eps_g,
    float* __restrict__ u_out, float* __restrict__ gu_out, int S)
{
    int b = blockIdx.x;
    int tid = threadIdx.x;
    int w = tid >> 6, l = tid & 63;

    float4 hr[4];
#pragma unroll
    for (int i = 0; i < 4; i++) {
        int k = b * 1024 + i * 256 + l * 4;
        float4 acc = *(const float4*)(psum + k);
        for (int s = 1; s < S; s++) {
            float4 t = *(const float4*)(psum + (size_t)s * 262144 + k);
            acc.x += t.x; acc.y += t.y; acc.z += t.z; acc.w += t.w;
        }
        float4 bb = *(const float4*)(b2 + i * 256 + l * 4);
        acc.x = fmaxf(acc.x + bb.x, 0.f);
        acc.y = fmaxf(acc.y + bb.y, 0.f);
        acc.z = fmaxf(acc.z + bb.z, 0.f);
        acc.w = fmaxf(acc.w + bb.w, 0.f);
        hr[i] = acc;
    }

    int o = w;
    int rm = (o < 48) ? o : (48 + o);
    int rv = (o < 48) ? (o + 48) : (51 + o);
    float4 wm[4], wv[4];
    {
        const float* wp = WT + rm * 1024 + l * 4;
#pragma unroll
        for (int i = 0; i < 4; i++) wm[i] = *(const float4*)(wp + i * 256);
        wp = WT + rv * 1024 + l * 4;
#pragma unroll
        for (int i = 0; i < 4; i++) wv[i] = *(const float4*)(wp + i * 256);
    }

    while (o < 51) {
        int onext = o + 8;
        float4 wmn[4], wvn[4];
        if (onext < 51) {
            int rm2 = (onext < 48) ? onext : (48 + onext);
            int rv2 = (onext < 48) ? (onext + 48) : (51 + onext);
            const float* wp = WT + rm2 * 1024 + l * 4;
#pragma unroll
            for (int i = 0; i < 4; i++) wmn[i] = *(const float4*)(wp + i * 256);
            wp = WT + rv2 * 1024 + l * 4;
#pragma unroll
            for (int i = 0; i < 4; i++) wvn[i] = *(const float4*)(wp + i * 256);
        }
        float am = 0.f, av = 0.f;
#pragma unroll
        for (int i = 0; i < 4; i++) {
            am = fmaf(hr[i].x, wm[i].x, am);
            am = fmaf(hr[i].y, wm[i].y, am);
            am = fmaf(hr[i].z, wm[i].z, am);
            am = fmaf(hr[i].w, wm[i].w, am);
            av = fmaf(hr[i].x, wv[i].x, av);
            av = fmaf(hr[i].y, wv[i].y, av);
            av = fmaf(hr[i].z, wv[i].z, av);
            av = fmaf(hr[i].w, wv[i].w, av);
        }
#pragma unroll
        for (int s = 32; s; s >>= 1) {
            am += __shfl_xor(am, s, 64);
            av += __shfl_xor(av, s, 64);
        }
        if (l == 0) {
            if (o < 48) {
                float umu = tanhf(am + bum[o]);
                float uvar = expf(fmaxf(av + buv[o], -6.f));  // threshold(-6,-6)
                u_out[b * 48 + o] = umu + uvar * eps_u[b * 48 + o];
            } else {
                int n = o - 48;
                float gmu = tanhf(am + bgm[n]);
                float gpre = av + bgv[n];
                float gvar = expf(gpre > -6.f ? gpre : 6.f);  // threshold(-6,6)
                gu_out[b * 3 + n] = gmu + gvar * eps_g[b * 3 + n];
            }
        }
#pragma unroll
        for (int i = 0; i < 4; i++) { wm[i] = wmn[i]; wv[i] = wvn[i]; }
        o = onext;
    }
}

// ---------------------------------------------------------------------------
// composite_final: 256 blocks (one batch), 1024 threads (16 waves).
// Full 16 KB M-plane staged double-buffered; after the p-loop, x goes into
// reused plane-LDS and the global gu transform runs in-block -> out.
// ---------------------------------------------------------------------------
__global__ __launch_bounds__(1024) void composite_final(
    const float* __restrict__ M, const float* __restrict__ parts,
    const float* __restrict__ u, const float* __restrict__ gu,
    float* __restrict__ out)
{
    __shared__ float patch[4096];
    __shared__ float plane[2][4096];
    __shared__ float pc[16], psn[16], ptx[16], pty[16];
    int b = blockIdx.x;
    int tid = threadIdx.x;

    for (int i = tid; i < 4096; i += 1024) patch[i] = parts[i];
    if (tid < 16) {
        const float* up = u + (b * 16 + tid) * 3;
        float ang = up[0];
        pc[tid] = cosf(ang);
        psn[tid] = sinf(ang);
        ptx[tid] = up[1];
        pty[tid] = up[2];
    }

    const float* Mb = M + ((size_t)(b * 16) << 12);
    ((float4*)plane[0])[tid] = ((const float4*)Mb)[tid];
    float4 pfn = ((const float4*)(Mb + 4096))[tid];
    __syncthreads();

    int j = tid & 63;
    int i0 = (tid >> 6) * 4;
    float xnv = (float)(2 * j + 1) * (1.f / 64.f) - 1.f;

    float num[4] = {}, den[4] = {};

    for (int p = 0; p < 16; p++) {
        int cur = p & 1;
        if (p + 1 < 16) ((float4*)plane[1 - cur])[tid] = pfn;
        if (p + 2 < 16) pfn = ((const float4*)(Mb + ((size_t)(p + 2) << 12)))[tid];

        int dx = 8 * (p & 3) - 12;
        int dy = 8 * (p >> 2) - 12;
        float c = pc[p], s = psn[p], tx = ptx[p], ty = pty[p];

        float ax = fminf(fmaxf(32.f * tx, -16384.f), 16384.f);
        float fax = floorf(ax);
        float wx = ax - fax;
        int ix = (int)fax;
        float ay = fminf(fmaxf(32.f * ty, -16384.f), 16384.f);
        float fay = floorf(ay);
        float wy = ay - fay;
        int iy = (int)fay;
        int iY = iy + dy;

        int x0 = j + ix;
        int X = x0 + dx;
        bool vc0 = ((unsigned)x0 < 64u) && ((unsigned)X < 64u);
        bool vc1 = ((unsigned)(x0 + 1) < 64u) && ((unsigned)(X + 1) < 64u);
        float w0 = vc0 ? (1.f - wx) : 0.f;
        float w1 = vc1 ? wx : 0.f;
        int Xc0 = min(max(X, 0), 63);
        int Xc1 = min(max(X + 1, 0), 63);

        const float* pl = plane[cur];
        float R[5];
#pragma unroll
        for (int r = 0; r < 5; r++) {
            int i = i0 + r;
            int ri = i + iY;
            bool vr = ((unsigned)(i + iy) < 64u) && ((unsigned)ri < 64u);
            int ric = min(max(ri, 0), 63);
            const float* row = pl + (ric << 6);
            float val = fmaf(w0, row[Xc0], w1 * row[Xc1]);
            R[r] = vr ? val : 0.f;
        }

        float Ax = fmaf(c, xnv, tx);
        float Ay = fmaf(s, xnv, ty);
        int ox = 24 - dx, oy = 24 - dy;
        float oxf = (float)ox, oyf = (float)oy;
        const float* pp = patch + (p << 8);
#pragma unroll
        for (int r = 0; r < 4; r++) {
            int i = i0 + r;
            float km = fmaf(wy, R[r + 1] - R[r], R[r]);
            den[r] += km;

            float ynv = (float)(2 * i + 1) * (1.f / 64.f) - 1.f;
            float gx = fmaf(-s, ynv, Ax);
            float gy = fmaf(c, ynv, Ay);
            float xs = fmaf(gx, 32.f, 31.5f);
            float ysv = fmaf(gy, 32.f, 31.5f);
            if (xs >= oxf - 1.f && xs < oxf + 16.f &&
                ysv >= oyf - 1.f && ysv < oyf + 16.f) {
                float xf = floorf(xs), yf = floorf(ysv);
                float wxx = xs - xf, wyy = ysv - yf;
                int a0 = (int)yf - oy;
                int b0c = (int)xf - ox;
                float v00 = 0.f, v10 = 0.f, v01 = 0.f, v11 = 0.f;
                if ((unsigned)a0 < 16u) {
                    const float* pr = pp + a0 * 16;
                    if ((unsigned)b0c < 16u) v00 = pr[b0c];
                    if ((unsigned)(b0c + 1) < 16u) v10 = pr[b0c + 1];
                }
                if ((unsigned)(a0 + 1) < 16u) {
                    const float* pr = pp + (a0 + 1) * 16;
                    if ((unsigned)b0c < 16u) v01 = pr[b0c];
                    if ((unsigned)(b0c + 1) < 16u) v11 = pr[b0c + 1];
                }
                float top = fmaf(wxx, v10 - v00, v00);
                float bot = fmaf(wxx, v11 - v01, v01);
                float xp = fmaf(wyy, bot - top, top);
                num[r] = fmaf(xp, km, num[r]);
            }
        }
        __syncthreads();
    }

    float* xl = plane[0];
#pragma unroll
    for (int r = 0; r < 4; r++) {
        float d = (den[r] == 0.f) ? 1.f : den[r];
        xl[(i0 + r) * 64 + j] = num[r] / d;
    }
    __syncthreads();

    float ang = gu[b * 3 + 0], gtx = gu[b * 3 + 1], gty = gu[b * 3 + 2];
    float cg = cosf(ang), sg = sinf(ang);
    float* ob = out + ((size_t)b << 12);
#pragma unroll
    for (int r = 0; r < 4; r++) {
        int i = i0 + r;
        float ynv = (float)(2 * i + 1) * (1.f / 64.f) - 1.f;
        float gx = cg * xnv - sg * ynv + gtx;
        float gy = sg * xnv + cg * ynv + gty;
        gx = fminf(fmaxf(gx, -8.f), 8.f);
        gy = fminf(fmaxf(gy, -8.f), 8.f);
        float xs = fmaf(gx, 32.f, 31.5f);
        float ysv = fmaf(gy, 32.f, 31.5f);
        float xf = floorf(xs), yf = floorf(ysv);
        float wx = xs - xf, wy = ysv - yf;
        int x0 = (int)xf, y0 = (int)yf;
        float v00 = 0.f, v10 = 0.f, v01 = 0.f, v11 = 0.f;
        bool vx0 = (unsigned)x0 < 64u, vx1 = (unsigned)(x0 + 1) < 64u;
        if ((unsigned)y0 < 64u) {
            const float* row = xl + y0 * 64;
            if (vx0) v00 = row[x0];
            if (vx1) v10 = row[x0 + 1];
        }
        if ((unsigned)(y0 + 1) < 64u) {
            const float* row = xl + (y0 + 1) * 64;
            if (vx0) v01 = row[x0];
            if (vx1) v11 = row[x0 + 1];
        }
        float top = fmaf(wx, v10 - v00, v00);
        float bot = fmaf(wx, v11 - v01, v01);
        ob[i * 64 + j] = fmaf(wy, bot - top, top);
    }
}

// ---------------------------------------------------------------------------
extern "C" void kernel_launch(void* const* d_in, const int* in_sizes, int n_in,
                              void* d_out, int out_size, void* d_ws, size_t ws_size,
                              hipStream_t stream)
{
    (void)in_sizes; (void)n_in; (void)out_size; (void)ws_size;
    const float* inputs = (const float*)d_in[0];
    const float* W1  = (const float*)d_in[1];
    const float* b1  = (const float*)d_in[2];
    const float* W2  = (const float*)d_in[3];
    const float* b2  = (const float*)d_in[4];
    const float* Wum = (const float*)d_in[5];
    const float* bum = (const float*)d_in[6];
    const float* Wuv = (const float*)d_in[7];
    const float* buv = (const float*)d_in[8];
    const float* Wgm = (const float*)d_in[9];
    const float* bgm = (const float*)d_in[10];
    const float* Wgv = (const float*)d_in[11];
    const float* bgv = (const float*)d_in[12];
    const float* Wz  = (const float*)d_in[13];
    const float* Mm  = (const float*)d_in[14];
    const float* eps_u = (const float*)d_in[15];
    const float* eps_g = (const float*)d_in[16];

    float* ws = (float*)d_ws;
    float* psum      = ws;                     // 16 x 262144 = 4,194,304
    float* u_buf     = ws + 4194304;           // 12,288
    float* gu_buf    = u_buf + 12288;          // 768
    float* parts_buf = gu_buf + 768;           // 4,096
    float* WTh_buf   = parts_buf + 4096;       // 104,448
    unsigned short* us = (unsigned short*)(WTh_buf + 104448);
    unsigned short* Ahi   = us;                 // 1,048,576
    unsigned short* Alo   = Ahi + 1048576;
    unsigned short* W1Thi = Alo + 1048576;      // 4,194,304
    unsigned short* W1Tlo = W1Thi + 4194304;
    unsigned short* W2Thi = W1Tlo + 4194304;    // 1,048,576
    unsigned short* W2Tlo = W2Thi + 1048576;
    unsigned short* H1hi  = W2Tlo + 1048576;    // 262,144
    unsigned short* H1lo  = H1hi + 262144;

    // Preprocessing
    prep_all<<<9640, 256, 0, stream>>>(inputs, W1, W2, Wum, Wuv, Wgm, Wgv, Wz,
                                       Ahi, Alo, W1Thi, W1Tlo, W2Thi, W2Tlo,
                                       WTh_buf, parts_buf);

    // MLP layer 1: [256,4096] @ [4096,1024], 128x128 tiles, split-K=16
    gemm_bf16x3_128<<<dim3(8, 2, SPLITK1), 256, 0, stream>>>(
        Ahi, Alo, W1Thi, W1Tlo, psum, 4096, 4096 / SPLITK1);
    reduce_bias_relu_split<<<1024, 256, 0, stream>>>(psum, b1, H1hi, H1lo, SPLITK1);
    // MLP layer 2: [256,1024] @ [1024,1024], 128x128 tiles, split-K=16 (nkt=1)
    gemm_bf16x3_128<<<dim3(8, 2, SPLITK2), 256, 0, stream>>>(
        H1hi, H1lo, W2Thi, W2Tlo, psum, 1024, 1024 / SPLITK2);
    // Heads (fused layer-2 reduce, S=16) -> u [256,48], gu [256,3]
    heads_v3<<<256, 512, 0, stream>>>(psum, b2, WTh_buf, bum, buv, bgm, bgv,
                                      eps_u, eps_g, u_buf, gu_buf, SPLITK2);
    // Compositing + global transform -> out [256,1,64,64]
    composite_final<<<256, 1024, 0, stream>>>(Mm, parts_buf, u_buf, gu_buf,
                                              (float*)d_out);
}

// Round 15
// 198.068 us; speedup vs baseline: 1.4363x; 1.4363x over previous
//
#include <hip/hip_runtime.h>
#include <math.h>

// Problem constants: B=256, H=W=64, P=16, PH=PW=16, ZD=32, HD=1024, UD=3, IN=4096
#define SPLITK 8

typedef __bf16 bf16x8 __attribute__((ext_vector_type(8)));
typedef float  f32x4  __attribute__((ext_vector_type(4)));

__device__ inline unsigned short bf16rne(float x) {
    unsigned int u = __float_as_uint(x);
    unsigned int r = u + 0x7FFFu + ((u >> 16) & 1u);
    return (unsigned short)(r >> 16);
}
__device__ inline float bf16tof(unsigned short h) {
    return __uint_as_float(((unsigned int)h) << 16);
}

// ---------------------------------------------------------------------------
// prep_all: fused independent preprocessing.
//  [0,4096)     : W1 [4096,1024] -> W1T{hi,lo} transposed split (32x32 tiles)
//  [4096,5120)  : inputs fp32 -> Ahi/Alo bf16 split, float4-vectorized
//  [5120,6144)  : W2 [1024,1024] -> W2T{hi,lo}
//  [6144,6552)  : head weights -> k-major WT[102][1024] fp32
//  [6552,6568)  : parts = sigmoid(colsum Wz)
// ---------------------------------------------------------------------------
__global__ __launch_bounds__(256) void prep_all(
    const float* __restrict__ inputs,
    const float* __restrict__ W1, const float* __restrict__ W2,
    const float* __restrict__ Wum, const float* __restrict__ Wuv,
    const float* __restrict__ Wgm, const float* __restrict__ Wgv,
    const float* __restrict__ Wz,
    unsigned short* __restrict__ Ahi, unsigned short* __restrict__ Alo,
    unsigned short* __restrict__ W1Thi, unsigned short* __restrict__ W1Tlo,
    unsigned short* __restrict__ W2Thi, unsigned short* __restrict__ W2Tlo,
    float* __restrict__ WT, float* __restrict__ partsb)
{
    __shared__ float t[32][33];
    int bid = blockIdx.x;
    int tid = threadIdx.x;
    if (bid < 4096 || (bid >= 5120 && bid < 6144)) {
        const float* W = (bid < 4096) ? W1 : W2;
        unsigned short* Thi = (bid < 4096) ? W1Thi : W2Thi;
        unsigned short* Tlo = (bid < 4096) ? W1Tlo : W2Tlo;
        int K = (bid < 4096) ? 4096 : 1024;
        int b2 = (bid < 4096) ? bid : (bid - 5120);
        int n0 = (b2 & 31) * 32, k0 = (b2 >> 5) * 32;
        int c = tid & 31, r0 = tid >> 5;
#pragma unroll
        for (int i = 0; i < 4; i++)
            t[r0 + 8 * i][c] = W[(size_t)(k0 + r0 + 8 * i) * 1024 + n0 + c];
        __syncthreads();
        int kk = tid & 31, n1 = tid >> 5;
#pragma unroll
        for (int i = 0; i < 4; i++) {
            float x = t[kk][n1 + 8 * i];
            unsigned short h = bf16rne(x);
            unsigned short l = bf16rne(x - bf16tof(h));
            size_t o = (size_t)(n0 + n1 + 8 * i) * K + k0 + kk;
            Thi[o] = h;
            Tlo[o] = l;
        }
    } else if (bid < 5120) {
        // input conversion, float4-vectorized (G13): 1024 blocks x 1024 elems
        int id = ((bid - 4096) * 256 + tid) * 4;
        float4 x = *(const float4*)(inputs + id);
        ushort4 h, l;
        h.x = bf16rne(x.x); l.x = bf16rne(x.x - bf16tof(h.x));
        h.y = bf16rne(x.y); l.y = bf16rne(x.y - bf16tof(h.y));
        h.z = bf16rne(x.z); l.z = bf16rne(x.z - bf16tof(h.z));
        h.w = bf16rne(x.w); l.w = bf16rne(x.w - bf16tof(h.w));
        *(ushort4*)(Ahi + id) = h;
        *(ushort4*)(Alo + id) = l;
    } else if (bid < 6552) {
        int id = (bid - 6144) * 256 + tid;
        int o = id >> 10;
        int k = id & 1023;
        float v;
        if (o < 48)       v = Wum[k * 48 + o];
        else if (o < 96)  v = Wuv[k * 48 + (o - 48)];
        else if (o < 99)  v = Wgm[k * 3 + (o - 96)];
        else              v = Wgv[k * 3 + (o - 99)];
        WT[id] = v;
    } else {
        int idx = (bid - 6552) * 256 + tid;
        float s = 0.f;
#pragma unroll
        for (int z = 0; z < 32; z++) s += Wz[z * 4096 + idx];
        partsb[idx] = 1.f / (1.f + expf(-s));
    }
}

// ---------------------------------------------------------------------------
// GEMM bf16x3 (fp32-accurate): psum[z] = A[256,Kc] @ B^T-tiles.
// 64x64 tile, 4 waves (2x2), 16x16x32 MFMA, XOR-swizzled LDS.  [r11-proven]
// ---------------------------------------------------------------------------
__global__ __launch_bounds__(256) void gemm_bf16x3(
    const unsigned short* __restrict__ Ahi, const unsigned short* __restrict__ Alo,
    const unsigned short* __restrict__ Bhi, const unsigned short* __restrict__ Blo,
    float* __restrict__ psum, int K, int kchunk)
{
    __shared__ unsigned short Ah[4096], Al[4096], Bh[4096], Bl[4096];
    int tid = threadIdx.x;
    int n0 = blockIdx.x * 64, m0 = blockIdx.y * 64;
    int kb = blockIdx.z * kchunk;
    int wid = tid >> 6, lane = tid & 63;
    int wm = wid & 1, wn = wid >> 1;
    int lm = lane & 15, q = lane >> 4;

    int r0 = tid >> 3, ch0 = tid & 7;
    int r1 = (tid + 256) >> 3, ch1 = (tid + 256) & 7;
    int l0 = r0 * 64 + 8 * (ch0 ^ (r0 & 7));
    int l1 = r1 * 64 + 8 * (ch1 ^ (r1 & 7));
    size_t ga0 = (size_t)(m0 + r0) * K + kb + ch0 * 8;
    size_t ga1 = (size_t)(m0 + r1) * K + kb + ch1 * 8;
    size_t gb0 = (size_t)(n0 + r0) * K + kb + ch0 * 8;
    size_t gb1 = (size_t)(n0 + r1) * K + kb + ch1 * 8;

    f32x4 acc[2][2] = {};

    int nkt = kchunk >> 6;
    uint4 vah0, vah1, val0, val1, vbh0, vbh1, vbl0, vbl1;
    vah0 = *(const uint4*)(Ahi + ga0);
    vah1 = *(const uint4*)(Ahi + ga1);
    val0 = *(const uint4*)(Alo + ga0);
    val1 = *(const uint4*)(Alo + ga1);
    vbh0 = *(const uint4*)(Bhi + gb0);
    vbh1 = *(const uint4*)(Bhi + gb1);
    vbl0 = *(const uint4*)(Blo + gb0);
    vbl1 = *(const uint4*)(Blo + gb1);

    int frm0 = (wm * 32 + lm) * 64;
    int frm1 = (wm * 32 + 16 + lm) * 64;
    int frn0 = (wn * 32 + lm) * 64;
    int frn1 = (wn * 32 + 16 + lm) * 64;
    int sw = lm & 7;

    for (int kt = 0; kt < nkt; kt++) {
        __syncthreads();
        *(uint4*)(Ah + l0) = vah0;
        *(uint4*)(Ah + l1) = vah1;
        *(uint4*)(Al + l0) = val0;
        *(uint4*)(Al + l1) = val1;
        *(uint4*)(Bh + l0) = vbh0;
        *(uint4*)(Bh + l1) = vbh1;
        *(uint4*)(Bl + l0) = vbl0;
        *(uint4*)(Bl + l1) = vbl1;
        __syncthreads();
        if (kt + 1 < nkt) {
            size_t o = (size_t)(kt + 1) * 64;
            vah0 = *(const uint4*)(Ahi + ga0 + o);
            vah1 = *(const uint4*)(Ahi + ga1 + o);
            val0 = *(const uint4*)(Alo + ga0 + o);
            val1 = *(const uint4*)(Alo + ga1 + o);
            vbh0 = *(const uint4*)(Bhi + gb0 + o);
            vbh1 = *(const uint4*)(Bhi + gb1 + o);
            vbl0 = *(const uint4*)(Blo + gb0 + o);
            vbl1 = *(const uint4*)(Blo + gb1 + o);
        }
#pragma unroll
        for (int ks = 0; ks < 2; ks++) {
            int cidx = 8 * (((ks << 2) + q) ^ sw);
            bf16x8 ah0 = *(const bf16x8*)(Ah + frm0 + cidx);
            bf16x8 ah1 = *(const bf16x8*)(Ah + frm1 + cidx);
            bf16x8 al0 = *(const bf16x8*)(Al + frm0 + cidx);
            bf16x8 al1 = *(const bf16x8*)(Al + frm1 + cidx);
            bf16x8 bh0 = *(const bf16x8*)(Bh + frn0 + cidx);
            bf16x8 bh1 = *(const bf16x8*)(Bh + frn1 + cidx);
            bf16x8 bl0 = *(const bf16x8*)(Bl + frn0 + cidx);
            bf16x8 bl1 = *(const bf16x8*)(Bl + frn1 + cidx);
            acc[0][0] = __builtin_amdgcn_mfma_f32_16x16x32_bf16(ah0, bh0, acc[0][0], 0, 0, 0);
            acc[0][0] = __builtin_amdgcn_mfma_f32_16x16x32_bf16(ah0, bl0, acc[0][0], 0, 0, 0);
            acc[0][0] = __builtin_amdgcn_mfma_f32_16x16x32_bf16(al0, bh0, acc[0][0], 0, 0, 0);
            acc[0][1] = __builtin_amdgcn_mfma_f32_16x16x32_bf16(ah0, bh1, acc[0][1], 0, 0, 0);
            acc[0][1] = __builtin_amdgcn_mfma_f32_16x16x32_bf16(ah0, bl1, acc[0][1], 0, 0, 0);
            acc[0][1] = __builtin_amdgcn_mfma_f32_16x16x32_bf16(al0, bh1, acc[0][1], 0, 0, 0);
            acc[1][0] = __builtin_amdgcn_mfma_f32_16x16x32_bf16(ah1, bh0, acc[1][0], 0, 0, 0);
            acc[1][0] = __builtin_amdgcn_mfma_f32_16x16x32_bf16(ah1, bl0, acc[1][0], 0, 0, 0);
            acc[1][0] = __builtin_amdgcn_mfma_f32_16x16x32_bf16(al1, bh0, acc[1][0], 0, 0, 0);
            acc[1][1] = __builtin_amdgcn_mfma_f32_16x16x32_bf16(ah1, bh1, acc[1][1], 0, 0, 0);
            acc[1][1] = __builtin_amdgcn_mfma_f32_16x16x32_bf16(ah1, bl1, acc[1][1], 0, 0, 0);
            acc[1][1] = __builtin_amdgcn_mfma_f32_16x16x32_bf16(al1, bh1, acc[1][1], 0, 0, 0);
        }
    }

    float* op = psum + (size_t)blockIdx.z * (256 * 1024);
#pragma unroll
    for (int mt = 0; mt < 2; mt++)
#pragma unroll
        for (int nt = 0; nt < 2; nt++) {
            int row = m0 + wm * 32 + mt * 16 + q * 4;
            int col = n0 + wn * 32 + nt * 16 + lm;
#pragma unroll
            for (int r = 0; r < 4; r++)
                op[(size_t)(row + r) * 1024 + col] = acc[mt][nt][r];
        }
}

// ---------------------------------------------------------------------------
// Reduce layer-1 partials + bias + relu -> bf16 hi/lo split.
// float4/thread, grid = 256 blocks (262144 / (256*4)).
// ---------------------------------------------------------------------------
__global__ __launch_bounds__(256) void reduce_bias_relu_split(
    const float* __restrict__ psum, const float* __restrict__ bias,
    unsigned short* __restrict__ hi, unsigned short* __restrict__ lo)
{
    int i = (blockIdx.x * 256 + threadIdx.x) * 4;
    float4 v = *(const float4*)(psum + i);
#pragma unroll
    for (int s = 1; s < SPLITK; s++) {
        float4 t = *(const float4*)(psum + (size_t)s * 262144 + i);
        v.x += t.x; v.y += t.y; v.z += t.z; v.w += t.w;
    }
    float4 bb = *(const float4*)(bias + (i & 1023));
    v.x = fmaxf(v.x + bb.x, 0.f);
    v.y = fmaxf(v.y + bb.y, 0.f);
    v.z = fmaxf(v.z + bb.z, 0.f);
    v.w = fmaxf(v.w + bb.w, 0.f);
    ushort4 h, l;
    h.x = bf16rne(v.x); l.x = bf16rne(v.x - bf16tof(h.x));
    h.y = bf16rne(v.y); l.y = bf16rne(v.y - bf16tof(h.y));
    h.z = bf16rne(v.z); l.z = bf16rne(v.z - bf16tof(h.z));
    h.w = bf16rne(v.w); l.w = bf16rne(v.w - bf16tof(h.w));
    *(ushort4*)(hi + i) = h;
    *(ushort4*)(lo + i) = l;
}

// ---------------------------------------------------------------------------
// heads_v3: fused layer-2 split-K reduce + head matvecs.  [r11-proven]
// ---------------------------------------------------------------------------
__global__ __launch_bounds__(512) void heads_v3(
    const float* __restrict__ psum, const float* __restrict__ b2,
    const float* __restrict__ WT,
    const float* __restrict__ bum, const float* __restrict__ buv,
    const float* __restrict__ bgm, const float* __restrict__ bgv,
    const float* __restrict__ eps_u, const float* __restrict__ eps_g,
    float* __restrict__ u_out, float* __restrict__ gu_out)
{
    int b = blockIdx.x;
    int tid = threadIdx.x;
    int w = tid >> 6, l = tid & 63;

    float4 hr[4];
#pragma unroll
    for (int i = 0; i < 4; i++) {
        int k = b * 1024 + i * 256 + l * 4;
        float4 acc = *(const float4*)(psum + k);
#pragma unroll
        for (int s = 1; s < SPLITK; s++) {
            float4 t = *(const float4*)(psum + (size_t)s * 262144 + k);
            acc.x += t.x; acc.y += t.y; acc.z += t.z; acc.w += t.w;
        }
        float4 bb = *(const float4*)(b2 + i * 256 + l * 4);
        acc.x = fmaxf(acc.x + bb.x, 0.f);
        acc.y = fmaxf(acc.y + bb.y, 0.f);
        acc.z = fmaxf(acc.z + bb.z, 0.f);
        acc.w = fmaxf(acc.w + bb.w, 0.f);
        hr[i] = acc;
    }

    int o = w;
    int rm = (o < 48) ? o : (48 + o);
    int rv = (o < 48) ? (o + 48) : (51 + o);
    float4 wm[4], wv[4];
    {
        const float* wp = WT + rm * 1024 + l * 4;
#pragma unroll
        for (int i = 0; i < 4; i++) wm[i] = *(const float4*)(wp + i * 256);
        wp = WT + rv * 1024 + l * 4;
#pragma unroll
        for (int i = 0; i < 4; i++) wv[i] = *(const float4*)(wp + i * 256);
    }

    while (o < 51) {
        int onext = o + 8;
        float4 wmn[4], wvn[4];
        if (onext < 51) {
            int rm2 = (onext < 48) ? onext : (48 + onext);
            int rv2 = (onext < 48) ? (onext + 48) : (51 + onext);
            const float* wp = WT + rm2 * 1024 + l * 4;
#pragma unroll
            for (int i = 0; i < 4; i++) wmn[i] = *(const float4*)(wp + i * 256);
            wp = WT + rv2 * 1024 + l * 4;
#pragma unroll
            for (int i = 0; i < 4; i++) wvn[i] = *(const float4*)(wp + i * 256);
        }
        float am = 0.f, av = 0.f;
#pragma unroll
        for (int i = 0; i < 4; i++) {
            am = fmaf(hr[i].x, wm[i].x, am);
            am = fmaf(hr[i].y, wm[i].y, am);
            am = fmaf(hr[i].z, wm[i].z, am);
            am = fmaf(hr[i].w, wm[i].w, am);
            av = fmaf(hr[i].x, wv[i].x, av);
            av = fmaf(hr[i].y, wv[i].y, av);
            av = fmaf(hr[i].z, wv[i].z, av);
            av = fmaf(hr[i].w, wv[i].w, av);
        }
#pragma unroll
        for (int s = 32; s; s >>= 1) {
            am += __shfl_xor(am, s, 64);
            av += __shfl_xor(av, s, 64);
        }
        if (l == 0) {
            if (o < 48) {
                float umu = tanhf(am + bum[o]);
                float uvar = expf(fmaxf(av + buv[o], -6.f));  // threshold(-6,-6)
                u_out[b * 48 + o] = umu + uvar * eps_u[b * 48 + o];
            } else {
                int n = o - 48;
                float gmu = tanhf(am + bgm[n]);
                float gpre = av + bgv[n];
                float gvar = expf(gpre > -6.f ? gpre : 6.f);  // threshold(-6,6)
                gu_out[b * 3 + n] = gmu + gvar * eps_g[b * 3 + n];
            }
        }
#pragma unroll
        for (int i = 0; i < 4; i++) { wm[i] = wmn[i]; wv[i] = wvn[i]; }
        o = onext;
    }
}

// ---------------------------------------------------------------------------
// composite_final: 256 blocks (one batch), 1024 threads (16 waves).
// Full 16 KB M-plane staged double-buffered; after the p-loop, x goes into
// reused plane-LDS and the global gu transform runs in-block -> out.
// [r11-proven]
// ---------------------------------------------------------------------------
__global__ __launch_bounds__(1024) void composite_final(
    const float* __restrict__ M, const float* __restrict__ parts,
    const float* __restrict__ u, const float* __restrict__ gu,
    float* __restrict__ out)
{
    __shared__ float patch[4096];
    __shared__ float plane[2][4096];
    __shared__ float pc[16], psn[16], ptx[16], pty[16];
    int b = blockIdx.x;
    int tid = threadIdx.x;

    for (int i = tid; i < 4096; i += 1024) patch[i] = parts[i];
    if (tid < 16) {
        const float* up = u + (b * 16 + tid) * 3;
        float ang = up[0];
        pc[tid] = cosf(ang);
        psn[tid] = sinf(ang);
        ptx[tid] = up[1];
        pty[tid] = up[2];
    }

    const float* Mb = M + ((size_t)(b * 16) << 12);
    ((float4*)plane[0])[tid] = ((const float4*)Mb)[tid];
    float4 pfn = ((const float4*)(Mb + 4096))[tid];
    __syncthreads();

    int j = tid & 63;
    int i0 = (tid >> 6) * 4;
    float xnv = (float)(2 * j + 1) * (1.f / 64.f) - 1.f;

    float num[4] = {}, den[4] = {};

    for (int p = 0; p < 16; p++) {
        int cur = p & 1;
        if (p + 1 < 16) ((float4*)plane[1 - cur])[tid] = pfn;
        if (p + 2 < 16) pfn = ((const float4*)(Mb + ((size_t)(p + 2) << 12)))[tid];

        int dx = 8 * (p & 3) - 12;
        int dy = 8 * (p >> 2) - 12;
        float c = pc[p], s = psn[p], tx = ptx[p], ty = pty[p];

        float ax = fminf(fmaxf(32.f * tx, -16384.f), 16384.f);
        float fax = floorf(ax);
        float wx = ax - fax;
        int ix = (int)fax;
        float ay = fminf(fmaxf(32.f * ty, -16384.f), 16384.f);
        float fay = floorf(ay);
        float wy = ay - fay;
        int iy = (int)fay;
        int iY = iy + dy;

        int x0 = j + ix;
        int X = x0 + dx;
        bool vc0 = ((unsigned)x0 < 64u) && ((unsigned)X < 64u);
        bool vc1 = ((unsigned)(x0 + 1) < 64u) && ((unsigned)(X + 1) < 64u);
        float w0 = vc0 ? (1.f - wx) : 0.f;
        float w1 = vc1 ? wx : 0.f;
        int Xc0 = min(max(X, 0), 63);
        int Xc1 = min(max(X + 1, 0), 63);

        const float* pl = plane[cur];
        float R[5];
#pragma unroll
        for (int r = 0; r < 5; r++) {
            int i = i0 + r;
            int ri = i + iY;
            bool vr = ((unsigned)(i + iy) < 64u) && ((unsigned)ri < 64u);
            int ric = min(max(ri, 0), 63);
            const float* row = pl + (ric << 6);
            float val = fmaf(w0, row[Xc0], w1 * row[Xc1]);
            R[r] = vr ? val : 0.f;
        }

        float Ax = fmaf(c, xnv, tx);
        float Ay = fmaf(s, xnv, ty);
        int ox = 24 - dx, oy = 24 - dy;
        float oxf = (float)ox, oyf = (float)oy;
        const float* pp = patch + (p << 8);
#pragma unroll
        for (int r = 0; r < 4; r++) {
            int i = i0 + r;
            float km = fmaf(wy, R[r + 1] - R[r], R[r]);
            den[r] += km;

            float ynv = (float)(2 * i + 1) * (1.f / 64.f) - 1.f;
            float gx = fmaf(-s, ynv, Ax);
            float gy = fmaf(c, ynv, Ay);
            float xs = fmaf(gx, 32.f, 31.5f);
            float ysv = fmaf(gy, 32.f, 31.5f);
            if (xs >= oxf - 1.f && xs < oxf + 16.f &&
                ysv >= oyf - 1.f && ysv < oyf + 16.f) {
                float xf = floorf(xs), yf = floorf(ysv);
                float wxx = xs - xf, wyy = ysv - yf;
                int a0 = (int)yf - oy;
                int b0c = (int)xf - ox;
                float v00 = 0.f, v10 = 0.f, v01 = 0.f, v11 = 0.f;
                if ((unsigned)a0 < 16u) {
                    const float* pr = pp + a0 * 16;
                    if ((unsigned)b0c < 16u) v00 = pr[b0c];
                    if ((unsigned)(b0c + 1) < 16u) v10 = pr[b0c + 1];
                }
                if ((unsigned)(a0 + 1) < 16u) {
                    const float* pr = pp + (a0 + 1) * 16;
                    if ((unsigned)b0c < 16u) v01 = pr[b0c];
                    if ((unsigned)(b0c + 1) < 16u) v11 = pr[b0c + 1];
                }
                float top = fmaf(wxx, v10 - v00, v00);
                float bot = fmaf(wxx, v11 - v01, v01);
                float xp = fmaf(wyy, bot - top, top);
                num[r] = fmaf(xp, km, num[r]);
            }
        }
        __syncthreads();
    }

    float* xl = plane[0];
#pragma unroll
    for (int r = 0; r < 4; r++) {
        float d = (den[r] == 0.f) ? 1.f : den[r];
        xl[(i0 + r) * 64 + j] = num[r] / d;
    }
    __syncthreads();

    float ang = gu[b * 3 + 0], gtx = gu[b * 3 + 1], gty = gu[b * 3 + 2];
    float cg = cosf(ang), sg = sinf(ang);
    float* ob = out + ((size_t)b << 12);
#pragma unroll
    for (int r = 0; r < 4; r++) {
        int i = i0 + r;
        float ynv = (float)(2 * i + 1) * (1.f / 64.f) - 1.f;
        float gx = cg * xnv - sg * ynv + gtx;
        float gy = sg * xnv + cg * ynv + gty;
        gx = fminf(fmaxf(gx, -8.f), 8.f);
        gy = fminf(fmaxf(gy, -8.f), 8.f);
        float xs = fmaf(gx, 32.f, 31.5f);
        float ysv = fmaf(gy, 32.f, 31.5f);
        float xf = floorf(xs), yf = floorf(ysv);
        float wx = xs - xf, wy = ysv - yf;
        int x0 = (int)xf, y0 = (int)yf;
        float v00 = 0.f, v10 = 0.f, v01 = 0.f, v11 = 0.f;
        bool vx0 = (unsigned)x0 < 64u, vx1 = (unsigned)(x0 + 1) < 64u;
        if ((unsigned)y0 < 64u) {
            const float* row = xl + y0 * 64;
            if (vx0) v00 = row[x0];
            if (vx1) v10 = row[x0 + 1];
        }
        if ((unsigned)(y0 + 1) < 64u) {
            const float* row = xl + (y0 + 1) * 64;
            if (vx0) v01 = row[x0];
            if (vx1) v11 = row[x0 + 1];
        }
        float top = fmaf(wx, v10 - v00, v00);
        float bot = fmaf(wx, v11 - v01, v01);
        ob[i * 64 + j] = fmaf(wy, bot - top, top);
    }
}

// ---------------------------------------------------------------------------
extern "C" void kernel_launch(void* const* d_in, const int* in_sizes, int n_in,
                              void* d_out, int out_size, void* d_ws, size_t ws_size,
                              hipStream_t stream)
{
    (void)in_sizes; (void)n_in; (void)out_size; (void)ws_size;
    const float* inputs = (const float*)d_in[0];
    const float* W1  = (const float*)d_in[1];
    const float* b1  = (const float*)d_in[2];
    const float* W2  = (const float*)d_in[3];
    const float* b2  = (const float*)d_in[4];
    const float* Wum = (const float*)d_in[5];
    const float* bum = (const float*)d_in[6];
    const float* Wuv = (const float*)d_in[7];
    const float* buv = (const float*)d_in[8];
    const float* Wgm = (const float*)d_in[9];
    const float* bgm = (const float*)d_in[10];
    const float* Wgv = (const float*)d_in[11];
    const float* bgv = (const float*)d_in[12];
    const float* Wz  = (const float*)d_in[13];
    const float* Mm  = (const float*)d_in[14];
    const float* eps_u = (const float*)d_in[15];
    const float* eps_g = (const float*)d_in[16];

    float* ws = (float*)d_ws;
    float* psum      = ws;                     // 8 x 262144 = 2,097,152
    float* u_buf     = ws + 2097152;           // 12,288
    float* gu_buf    = u_buf + 12288;          // 768
    float* parts_buf = gu_buf + 768;           // 4,096
    float* WTh_buf   = parts_buf + 4096;       // 104,448
    unsigned short* us = (unsigned short*)(WTh_buf + 104448);
    unsigned short* Ahi   = us;                 // 1,048,576
    unsigned short* Alo   = Ahi + 1048576;
    unsigned short* W1Thi = Alo + 1048576;      // 4,194,304
    unsigned short* W1Tlo = W1Thi + 4194304;
    unsigned short* W2Thi = W1Tlo + 4194304;    // 1,048,576
    unsigned short* W2Tlo = W2Thi + 1048576;
    unsigned short* H1hi  = W2Tlo + 1048576;    // 262,144
    unsigned short* H1lo  = H1hi + 262144;

    // Preprocessing
    prep_all<<<6568, 256, 0, stream>>>(inputs, W1, W2, Wum, Wuv, Wgm, Wgv, Wz,
                                       Ahi, Alo, W1Thi, W1Tlo, W2Thi, W2Tlo,
                                       WTh_buf, parts_buf);

    // MLP layer 1: [256,4096] @ [4096,1024], bf16x3 MFMA split-K=8
    gemm_bf16x3<<<dim3(16, 4, SPLITK), 256, 0, stream>>>(Ahi, Alo, W1Thi, W1Tlo,
                                                         psum, 4096, 4096 / SPLITK);
    reduce_bias_relu_split<<<256, 256, 0, stream>>>(psum, b1, H1hi, H1lo);
    // MLP layer 2: [256,1024] @ [1024,1024], split-K=8
    gemm_bf16x3<<<dim3(16, 4, SPLITK), 256, 0, stream>>>(H1hi, H1lo, W2Thi, W2Tlo,
                                                         psum, 1024, 1024 / SPLITK);
    // Heads (fused layer-2 reduce) -> u [256,48], gu [256,3]
    heads_v3<<<256, 512, 0, stream>>>(psum, b2, WTh_buf, bum, buv, bgm, bgv,
                                      eps_u, eps_g, u_buf, gu_buf);
    // Compositing + global transform -> out [256,1,64,64]
    composite_final<<<256, 1024, 0, stream>>>(Mm, parts_buf, u_buf, gu_buf,
                                              (float*)d_out);
}